// Round 3
// baseline (27225.879 us; speedup 1.0000x reference)
//
#include <hip/hip_runtime.h>
#include <hip/hip_fp16.h>
#include <stdint.h>

// ---------------------------------------------------------------------------
// SequentialEMGPoseLSTM: 2-layer LSTM (H=256, B=64, T=4096) + LeakyReLU+Linear
//
// R3 changes vs R2 (post-mortem: 1050 cy/step residual LDS conflicts from the
// padded o-gate layout; VALU tail overhead; 18 dispatches):
//  - Lane-interleaved LDS weight layout: instruction q reads lane-contiguous
//    16B chunks (stride-1 across the wave) -> conflict-free by construction.
//  - Bias + xw adds moved pre-shuffle, spread across the 4 k-slices (2 scalar
//    coalesced loads/thread); bsum LDS round-trip deleted.
//  - hbuf/abuf chunks padded to 16B multiples (80/48 halves) so b128 loads
//    stay b128 (previous 72/40 chunks were 8B-aligned -> split reads).
//  - xw buffer stored as f16: halves layer1 read bytes + workspace (Tc=512
//    often fits -> 10 dispatches).
// ---------------------------------------------------------------------------

#define T_SEQ 4096
#define NB    64
#define HID   256
#define G4    1024
#define INCH  16
#define OC    20

typedef _Float16 h2v   __attribute__((ext_vector_type(2)));
typedef _Float16 f16x8 __attribute__((ext_vector_type(8)));
typedef float    f32x4 __attribute__((ext_vector_type(4)));

__device__ __forceinline__ float fdot2(uint32_t a, uint32_t b, float c) {
  return __builtin_amdgcn_fdot2(__builtin_bit_cast(h2v, a),
                                __builtin_bit_cast(h2v, b), c, false);
}
__device__ __forceinline__ float sigf(float x) {
  x = fminf(fmaxf(x, -30.f), 30.f);
  return 1.f / (1.f + __expf(-x));
}
__device__ __forceinline__ float tanhf_fast(float x) {
  x = fminf(fmaxf(x, -15.f), 15.f);
  float e = __expf(-2.f * x);
  return (1.f - e) / (1.f + e);
}

#define PIN(x) asm volatile("" : "+v"(x))

// LDS layout:
//  w: lane-interleaved o-gate weights. u32 index (wave*16 + t)*256 + lane*4,
//     t = (j-6)*8 + hf*4 + q. Each b128 read: lane l at byte
//     waveBase + t*1024 + l*16 -> stride-1 across wave, conflict-free.
//  hbuf: 2 buffers x 4 chunks x 80 halves (chunk = 64 h values + pad, 160B).
//  abuf: 2 buffers x 8 chunks x 48 halves (chunk = 32 values + pad, 96B).
struct SmemR {
  uint32_t w[8 * 16 * 256];   // 131072 B
  __half hbuf[2][4 * 80];     // 1280 B
  union {
    uint32_t xb[512 * 8];     // layer0: packed x pairs [tt][dp], Tc<=512
    struct {
      __half abuf[2][8 * 48];
      __half whd[20 * 264];
      float  bh[20];
    } h1;
  } u;
};
struct SmemG {
  __half a[128 * 40];
  __half b[64 * 40];
};
union Smem { SmemR r; SmemG g; };

struct Params {
  const float* x;
  const __half *wh0, *wh1, *wi0, *wi1, *whd;
  const float  *bs0, *bs1, *bhd;
  float *h0s, *c0s, *h1s, *c1s;
  __half* h1w; const __half* h1r;
  __half* xww; const __half* xwr;
  float* y;
  int L, Tc, nch;
};

// ---------------------------------------------------------------------------
// Recurrent role: one block == one batch chain. 512 threads.
// slice = tid&3 covers k in [64*slice, 64*slice+64); rg = tid>>2 (0..127).
// Thread handles gate rows r = rg + 128*j, j=0..7 (j<6 reg, j>=6 LDS).
// Slice s owns the bias/xw add for rows rg+256s and rg+128+256s (j=2s,2s+1).
// Slice-0 threads apply activations for channels rg and rg+128.
// ---------------------------------------------------------------------------
template <int LAYER>
__device__ void role_rec(SmemR& S, int ch, const Params& P, int b) {
  if (ch < 0 || ch >= P.nch) return;
  const int tid   = threadIdx.x;
  const int slice = tid & 3;
  const int rg    = tid >> 2;
  const int wv    = tid >> 6;
  const int ln    = tid & 63;
  const int Tc    = P.Tc;
  const __half* whh = (LAYER == 0) ? P.wh0 : P.wh1;

  // Stage o-gate weight rows 768..1023 into lane-interleaved layout.
#pragma unroll
  for (int j = 0; j < 2; j++)
#pragma unroll
    for (int hf = 0; hf < 2; hf++)
#pragma unroll
      for (int q = 0; q < 4; q++) {
        const uint4 v = *(const uint4*)(whh + (768 + j * 128 + rg) * 256 +
                                        slice * 64 + hf * 32 + q * 8);
        *(uint4*)&S.w[(wv * 16 + j * 8 + hf * 4 + q) * 256 + ln * 4] = v;
      }

  const int t0 = ch * Tc;
  if (LAYER == 0) {
    for (int i = tid; i < Tc * 8; i += 512) {
      int dp = i / Tc, tt = i - dp * Tc;
      float v0 = P.x[(b * INCH + 2 * dp) * T_SEQ + t0 + tt];
      float v1 = P.x[(b * INCH + 2 * dp + 1) * T_SEQ + t0 + tt];
      uint32_t pv = (uint32_t)__half_as_ushort(__float2half(v0)) |
                    ((uint32_t)__half_as_ushort(__float2half(v1)) << 16);
      S.u.xb[tt * 8 + dp] = pv;
    }
  } else {
    for (int i = tid; i < OC * 256; i += 512) {
      int o = i >> 8, k = i & 255;
      S.u.h1.whd[o * 264 + k] = P.whd[i];
    }
    if (tid < OC) S.u.h1.bh[tid] = P.bhd[tid];
  }

  // Per-thread bias for rows j=2*slice, 2*slice+1.
  float bA, bB;
  {
    const float* bs = (LAYER == 0) ? P.bs0 : P.bs1;
    bA = bs[rg + 256 * slice];
    bB = bs[rg + 128 + 256 * slice];
  }

  // Register-resident weights: rows j=0..5, 64 halves each (32 packed u32).
  uint32_t wr[6][32];
#pragma unroll
  for (int j = 0; j < 6; j++) {
    const uint4* p = (const uint4*)(whh + (rg + 128 * j) * 256 + slice * 64);
#pragma unroll
    for (int q = 0; q < 8; q++) {
      uint4 v = p[q];
      wr[j][4 * q] = v.x; wr[j][4 * q + 1] = v.y;
      wr[j][4 * q + 2] = v.z; wr[j][4 * q + 3] = v.w;
    }
  }
#pragma unroll
  for (int j = 0; j < 6; j++)
#pragma unroll
    for (int q = 0; q < 32; q++) PIN(wr[j][q]);

  uint32_t wx[8][2];
  if (LAYER == 0) {
#pragma unroll
    for (int j = 0; j < 8; j++) {
      const uint32_t* p = (const uint32_t*)(P.wi0 + (rg + 128 * j) * INCH + slice * 4);
      wx[j][0] = p[0]; wx[j][1] = p[1];
    }
#pragma unroll
    for (int j = 0; j < 8; j++) { PIN(wx[j][0]); PIN(wx[j][1]); }
  }

  // State: slice-0 thread owns channels rg and rg+128 (fp32 h,c).
  float* hs = (LAYER == 0) ? P.h0s : P.h1s;
  float* cs = (LAYER == 0) ? P.c0s : P.c1s;
  float hA = 0.f, hB = 0.f, cA = 0.f, cB = 0.f;
  if (slice == 0) {
    if (ch != 0) {
      hA = hs[b * 256 + rg];       cA = cs[b * 256 + rg];
      hB = hs[b * 256 + rg + 128]; cB = cs[b * 256 + rg + 128];
    }
    __half* hb = S.hbuf[0];
    hb[(rg >> 6) * 80 + (rg & 63)] = __float2half(hA);
    hb[(2 + (rg >> 6)) * 80 + (rg & 63)] = __float2half(hB);
  }
  // xw prefetch (layer1): rows rg+256*slice, rg+128+256*slice at tt=0.
  float xwA = 0.f, xwB = 0.f;
  if (LAYER == 1) {
    const __half* base = P.xwr + (size_t)b * G4;
    xwA = __half2float(base[rg + 256 * slice]);
    xwB = __half2float(base[rg + 128 + 256 * slice]);
  }
  __syncthreads();

  for (int tt = 0; tt < Tc; ++tt) {
    const __half* hb = S.hbuf[tt & 1];
    float acc[8];
#pragma unroll
    for (int j = 0; j < 8; j++) acc[j] = 0.f;

#pragma unroll
    for (int hf = 0; hf < 2; ++hf) {
      uint32_t hh[16];
      const uint4* hp = (const uint4*)(hb + slice * 80 + hf * 32);
#pragma unroll
      for (int q = 0; q < 4; q++) {
        uint4 v = hp[q];
        hh[4 * q] = v.x; hh[4 * q + 1] = v.y; hh[4 * q + 2] = v.z; hh[4 * q + 3] = v.w;
      }
#pragma unroll
      for (int j = 0; j < 6; j++) {
        float a = acc[j];
#pragma unroll
        for (int q = 0; q < 16; q++) a = fdot2(wr[j][hf * 16 + q], hh[q], a);
        acc[j] = a;
      }
#pragma unroll
      for (int j = 0; j < 2; j++) {
        float a = acc[6 + j];
#pragma unroll
        for (int q = 0; q < 4; q++) {
          const uint4 v = *(const uint4*)&S.w[(wv * 16 + j * 8 + hf * 4 + q) * 256 + ln * 4];
          a = fdot2(v.x, hh[4 * q], a);
          a = fdot2(v.y, hh[4 * q + 1], a);
          a = fdot2(v.z, hh[4 * q + 2], a);
          a = fdot2(v.w, hh[4 * q + 3], a);
        }
        acc[6 + j] = a;
      }
    }
    if (LAYER == 0) {
      uint32_t xv0 = S.u.xb[tt * 8 + 2 * slice];
      uint32_t xv1 = S.u.xb[tt * 8 + 2 * slice + 1];
#pragma unroll
      for (int j = 0; j < 8; j++) {
        acc[j] = fdot2(wx[j][0], xv0, acc[j]);
        acc[j] = fdot2(wx[j][1], xv1, acc[j]);
      }
    }
    // Pre-shuffle bias (+xw) add: slice s covers rows j=2s, 2s+1 exactly once.
    acc[2 * slice] += bA;
    acc[2 * slice + 1] += bB;
    if (LAYER == 1) {
      acc[2 * slice] += xwA;
      acc[2 * slice + 1] += xwB;
      if (tt + 1 < Tc) {
        const __half* base = P.xwr + ((size_t)(tt + 1) * NB + b) * G4;
        xwA = __half2float(base[rg + 256 * slice]);
        xwB = __half2float(base[rg + 128 + 256 * slice]);
      }
    }
#pragma unroll
    for (int j = 0; j < 8; j++) {
      acc[j] += __shfl_xor(acc[j], 1);
      acc[j] += __shfl_xor(acc[j], 2);
    }

    if (slice == 0) {
      float iA = sigf(acc[0]), iB = sigf(acc[1]);
      float fA = sigf(acc[2]), fB = sigf(acc[3]);
      float gA = tanhf_fast(acc[4]), gB = tanhf_fast(acc[5]);
      float oA = sigf(acc[6]), oB = sigf(acc[7]);
      cA = fA * cA + iA * gA;
      cB = fB * cB + iB * gB;
      hA = oA * tanhf_fast(cA);
      hB = oB * tanhf_fast(cB);
      __half hA16 = __float2half(hA), hB16 = __float2half(hB);
      __half* hw = S.hbuf[(tt + 1) & 1];
      hw[(rg >> 6) * 80 + (rg & 63)] = hA16;
      hw[(2 + (rg >> 6)) * 80 + (rg & 63)] = hB16;
      if (LAYER == 0) {
        __half* dst = P.h1w + (size_t)(tt * NB + b) * 256;
        dst[rg] = hA16;
        dst[rg + 128] = hB16;
      } else {
        float aA = hA > 0.f ? hA : 0.01f * hA;
        float aB = hB > 0.f ? hB : 0.01f * hB;
        __half* ab = S.u.h1.abuf[tt & 1];
        ab[(rg >> 5) * 48 + (rg & 31)] = __float2half(aA);
        ab[(4 + (rg >> 5)) * 48 + (rg & 31)] = __float2half(aB);
      }
    }
    __syncthreads();

    // Head (layer1): 20 outputs x 8 lanes x 32 k. Reads abuf[tt&1]; that
    // buffer's next overwrite is 2 steps away behind an intervening barrier.
    if (LAYER == 1 && tid < OC * 8) {
      int o = tid >> 3, ks = tid & 7;
      const uint4* wp = (const uint4*)&S.u.h1.whd[o * 264 + ks * 32];
      const uint4* ap = (const uint4*)&S.u.h1.abuf[tt & 1][ks * 48];
      float a = 0.f;
#pragma unroll
      for (int q = 0; q < 4; q++) {
        uint4 w4 = wp[q];
        uint4 a4 = ap[q];
        a = fdot2(w4.x, a4.x, a);
        a = fdot2(w4.y, a4.y, a);
        a = fdot2(w4.z, a4.z, a);
        a = fdot2(w4.w, a4.w, a);
      }
      a += __shfl_xor(a, 1);
      a += __shfl_xor(a, 2);
      a += __shfl_xor(a, 4);
      if (ks == 0) P.y[(b * OC + o) * T_SEQ + t0 + tt] = a + S.u.h1.bh[o];
    }
  }
  if (slice == 0) {
    hs[b * 256 + rg] = hA;        cs[b * 256 + rg] = cA;
    hs[b * 256 + rg + 128] = hB;  cs[b * 256 + rg + 128] = cB;
  }
}

// ---------------------------------------------------------------------------
// GEMM role: xw1[tb, g] = sum_k h1[tb,k] * Wih1[g,k], f16 MFMA, f16 out.
// ---------------------------------------------------------------------------
__device__ void role_gemm(SmemG& S, int chG, const Params& P) {
  if (chG < 0 || chG >= P.nch) return;
  const int bid = blockIdx.x - 128;
  const int nt = bid & 15, mt = bid >> 4;
  const int tb0 = mt * 128, g0 = nt * 64;
  const int tid = threadIdx.x, lane = tid & 63, w = tid >> 6;
  const int wm = w & 3, wn = w >> 2;

  f32x4 cacc[2][2] = {};
  for (int kk = 0; kk < 256; kk += 32) {
    __syncthreads();
    {
      int row = tid >> 2, q = tid & 3;
      const uint4* src = (const uint4*)(P.h1r + (tb0 + row) * 256 + kk + q * 8);
      *(uint4*)&S.a[row * 40 + q * 8] = *src;
    }
    if (tid < 256) {
      int row = tid >> 2, q = tid & 3;
      const uint4* src = (const uint4*)(P.wi1 + (g0 + row) * 256 + kk + q * 8);
      *(uint4*)&S.b[row * 40 + q * 8] = *src;
    }
    __syncthreads();
    f16x8 af[2], bf[2];
#pragma unroll
    for (int mi = 0; mi < 2; mi++)
      af[mi] = *(const f16x8*)&S.a[(wm * 32 + mi * 16 + (lane & 15)) * 40 + (lane >> 4) * 8];
#pragma unroll
    for (int ni = 0; ni < 2; ni++)
      bf[ni] = *(const f16x8*)&S.b[(wn * 32 + ni * 16 + (lane & 15)) * 40 + (lane >> 4) * 8];
#pragma unroll
    for (int mi = 0; mi < 2; mi++)
#pragma unroll
      for (int ni = 0; ni < 2; ni++)
        cacc[mi][ni] = __builtin_amdgcn_mfma_f32_16x16x32_f16(af[mi], bf[ni], cacc[mi][ni], 0, 0, 0);
  }
#pragma unroll
  for (int mi = 0; mi < 2; mi++)
#pragma unroll
    for (int ni = 0; ni < 2; ni++) {
      int m = wm * 32 + mi * 16 + (lane >> 4) * 4;
      int n = g0 + wn * 32 + ni * 16 + (lane & 15);
#pragma unroll
      for (int r = 0; r < 4; r++)
        P.xww[(size_t)(tb0 + m + r) * G4 + n] = __float2half(cacc[mi][ni][r]);
    }
}

__global__ __launch_bounds__(512)
__attribute__((amdgpu_waves_per_eu(2, 2)))
void fused_kernel(Params P) {
  __shared__ Smem S;
  int bid = blockIdx.x;
  if (bid < 64)        role_rec<0>(S.r, P.L, P, bid);
  else if (bid < 128)  role_rec<1>(S.r, P.L - 2, P, bid - 64);
  else                 role_gemm(S.g, P.L - 1, P);
}

// ---------------------------------------------------------------------------
__global__ void prep_kernel(const float* Wih0, const float* Whh0,
                            const float* bih0, const float* bhh0,
                            const float* Wih1, const float* Whh1,
                            const float* bih1, const float* bhh1,
                            const float* Whead, const float* bhead,
                            __half* wh0, __half* wh1, __half* wi1, __half* wi0,
                            __half* whd, float* bs0, float* bs1, float* bhd) {
  int i = blockIdx.x * blockDim.x + threadIdx.x;
  if (i < G4 * HID) {
    wh0[i] = __float2half(Whh0[i]);
    wh1[i] = __float2half(Whh1[i]);
    wi1[i] = __float2half(Wih1[i]);
  }
  if (i < G4 * INCH) wi0[i] = __float2half(Wih0[i]);
  if (i < OC * HID)  whd[i] = __float2half(Whead[i]);
  if (i < G4) { bs0[i] = bih0[i] + bhh0[i]; bs1[i] = bih1[i] + bhh1[i]; }
  if (i < OC) bhd[i] = bhead[i];
}

// ---------------------------------------------------------------------------
extern "C" void kernel_launch(void* const* d_in, const int* in_sizes, int n_in,
                              void* d_out, int out_size, void* d_ws, size_t ws_size,
                              hipStream_t stream) {
  const float* x     = (const float*)d_in[0];
  const float* Wih0  = (const float*)d_in[1];
  const float* Whh0  = (const float*)d_in[2];
  const float* bih0  = (const float*)d_in[3];
  const float* bhh0  = (const float*)d_in[4];
  const float* Wih1  = (const float*)d_in[5];
  const float* Whh1  = (const float*)d_in[6];
  const float* bih1  = (const float*)d_in[7];
  const float* bhh1  = (const float*)d_in[8];
  const float* Whead = (const float*)d_in[9];
  const float* bhead = (const float*)d_in[10];
  float* y = (float*)d_out;

  char* ws = (char*)d_ws;
  size_t cur = 0;
  auto alloc = [&](size_t sz) -> char* {
    char* p = ws + cur;
    cur = (cur + sz + 255) & ~(size_t)255;
    return p;
  };
  __half* wh0 = (__half*)alloc(G4 * HID * 2);
  __half* wh1 = (__half*)alloc(G4 * HID * 2);
  __half* wi1 = (__half*)alloc(G4 * HID * 2);
  __half* wi0 = (__half*)alloc(G4 * INCH * 2);
  __half* whd = (__half*)alloc(OC * HID * 2);
  float* bs0 = (float*)alloc(G4 * 4);
  float* bs1 = (float*)alloc(G4 * 4);
  float* bhd = (float*)alloc(OC * 4);
  float* h0s = (float*)alloc(NB * HID * 4);
  float* c0s = (float*)alloc(NB * HID * 4);
  float* h1s = (float*)alloc(NB * HID * 4);
  float* c1s = (float*)alloc(NB * HID * 4);
  size_t fixed = cur;

  int Tc = 512;
  while (Tc > 64) {
    size_t need = fixed + 2 * ((size_t)Tc * NB * HID * 2 + 512) +
                  2 * ((size_t)Tc * NB * G4 * 2 + 512);
    if (need <= ws_size) break;
    Tc >>= 1;
  }
  __half* h1buf[2];
  __half* xwbuf[2];
  h1buf[0] = (__half*)alloc((size_t)Tc * NB * HID * 2);
  h1buf[1] = (__half*)alloc((size_t)Tc * NB * HID * 2);
  xwbuf[0] = (__half*)alloc((size_t)Tc * NB * G4 * 2);
  xwbuf[1] = (__half*)alloc((size_t)Tc * NB * G4 * 2);

  const int nch = T_SEQ / Tc;

  prep_kernel<<<(G4 * HID + 255) / 256, 256, 0, stream>>>(
      Wih0, Whh0, bih0, bhh0, Wih1, Whh1, bih1, bhh1, Whead, bhead,
      wh0, wh1, wi1, wi0, whd, bs0, bs1, bhd);

  const int ngemm = Tc * 8;
  for (int L = 0; L < nch + 2; ++L) {
    Params P;
    P.x = x;
    P.wh0 = wh0; P.wh1 = wh1; P.wi0 = wi0; P.wi1 = wi1; P.whd = whd;
    P.bs0 = bs0; P.bs1 = bs1; P.bhd = bhd;
    P.h0s = h0s; P.c0s = c0s; P.h1s = h1s; P.c1s = c1s;
    P.h1w = h1buf[L & 1];
    P.h1r = h1buf[(L + 1) & 1];
    P.xww = xwbuf[(L + 1) & 1];
    P.xwr = xwbuf[L & 1];
    P.y = y;
    P.L = L; P.Tc = Tc; P.nch = nch;
    fused_kernel<<<128 + ngemm, 512, 0, stream>>>(P);
  }
}

// Round 4
// 25333.154 us; speedup vs baseline: 1.0747x; 1.0747x over previous
//
#include <hip/hip_runtime.h>
#include <hip/hip_fp16.h>
#include <stdint.h>

// ---------------------------------------------------------------------------
// SequentialEMGPoseLSTM: 2-layer LSTM (H=256, B=64, T=4096) + LeakyReLU+Linear
//
// R4 changes vs R3 (post-mortem: acc[2*slice] dynamic indexing -> scratch
// spill, +70MB/dispatch HBM traffic, 2.4x step slowdown; abuf 96B stride
// bank collisions):
//  - Bias/xw pre-reduction adds via 4-way branch with LITERAL indices.
//  - __shfl_xor quad reduction -> DPP quad_perm v_add (no LDS pipe, sum
//    lands in all 4 quad lanes).
//  - Activation tail split across 2 lanes/quad (slice0: ch rg, slice1:
//    ch rg+128) -> half the serial transcendental chain.
//  - abuf back to 40-half (80B, bank-distinct) chunks; whd rows 272 halves.
//  - Tc fixed 256 (R2 proven config). Keep: lane-interleaved o-gate LDS
//    layout (conflict-free), f16 xw buffer, waves_per_eu(2,2), PINs.
// ---------------------------------------------------------------------------

#define T_SEQ 4096
#define NB    64
#define HID   256
#define G4    1024
#define INCH  16
#define OC    20
#define TCH   256

typedef _Float16 h2v   __attribute__((ext_vector_type(2)));
typedef _Float16 f16x8 __attribute__((ext_vector_type(8)));
typedef float    f32x4 __attribute__((ext_vector_type(4)));

__device__ __forceinline__ float fdot2(uint32_t a, uint32_t b, float c) {
  return __builtin_amdgcn_fdot2(__builtin_bit_cast(h2v, a),
                                __builtin_bit_cast(h2v, b), c, false);
}
__device__ __forceinline__ float sigf(float x) {
  x = fminf(fmaxf(x, -30.f), 30.f);
  return 1.f / (1.f + __expf(-x));
}
__device__ __forceinline__ float tanhf_fast(float x) {
  x = fminf(fmaxf(x, -15.f), 15.f);
  float e = __expf(-2.f * x);
  return (1.f - e) / (1.f + e);
}
// Quad butterfly add via DPP: after this, all 4 lanes of each quad hold the
// sum of the quad. quad_perm [1,0,3,2]=0xB1 (xor1), [2,3,0,1]=0x4E (xor2).
__device__ __forceinline__ float qsum4(float x) {
  int t = __builtin_amdgcn_mov_dpp(__float_as_int(x), 0xB1, 0xF, 0xF, true);
  x += __int_as_float(t);
  t = __builtin_amdgcn_mov_dpp(__float_as_int(x), 0x4E, 0xF, 0xF, true);
  return x + __int_as_float(t);
}

#define PIN(x) asm volatile("" : "+v"(x))

// LDS layout:
//  w: lane-interleaved o-gate weights. u32 index (wave*16 + t)*256 + lane*4,
//     t = (j-6)*8 + hf*4 + q. Each b128 read: lane l at byte
//     waveBase + t*1024 + l*16 -> stride-1 across wave, conflict-free.
//  hbuf: 2 buffers x 4 chunks x 80 halves (160B chunks, banks 0/8/16/24).
//  abuf: 2 buffers x 8 chunks x 40 halves (80B chunks, banks all distinct).
struct SmemR {
  uint32_t w[8 * 16 * 256];   // 131072 B
  __half hbuf[2][4 * 80];     // 1280 B
  union {
    uint32_t xb[TCH * 8];     // layer0: packed x pairs [tt][dp]
    struct {
      __half abuf[2][8 * 40];
      __half whd[20 * 272];
      float  bh[20];
    } h1;
  } u;
};
struct SmemG {
  __half a[128 * 40];
  __half b[64 * 40];
};
union Smem { SmemR r; SmemG g; };

struct Params {
  const float* x;
  const __half *wh0, *wh1, *wi0, *wi1, *whd;
  const float  *bs0, *bs1, *bhd;
  float *h0s, *c0s, *h1s, *c1s;
  __half* h1w; const __half* h1r;
  __half* xww; const __half* xwr;
  float* y;
  int L, Tc, nch;
};

// ---------------------------------------------------------------------------
// Recurrent role: one block == one batch chain. 512 threads.
// slice = tid&3 covers k in [64*slice, 64*slice+64); rg = tid>>2 (0..127).
// Thread handles gate rows r = rg + 128*j, j=0..7 (j<6 reg, j>=6 LDS).
// Row rg+128j: j even -> gate j/2 of channel rg; j odd -> of channel rg+128.
// Slice s pre-adds bias/xw for rows j=2s,2s+1. After DPP quad reduction all
// quad lanes hold all 8 sums; slice0 updates channel rg, slice1 rg+128.
// ---------------------------------------------------------------------------
template <int LAYER>
__device__ void role_rec(SmemR& S, int ch, const Params& P, int b) {
  if (ch < 0 || ch >= P.nch) return;
  const int tid   = threadIdx.x;
  const int slice = tid & 3;
  const int rg    = tid >> 2;
  const int wv    = tid >> 6;
  const int ln    = tid & 63;
  const int Tc    = P.Tc;
  const __half* whh = (LAYER == 0) ? P.wh0 : P.wh1;

  // Stage o-gate weight rows 768..1023 into lane-interleaved layout.
#pragma unroll
  for (int j = 0; j < 2; j++)
#pragma unroll
    for (int hf = 0; hf < 2; hf++)
#pragma unroll
      for (int q = 0; q < 4; q++) {
        const uint4 v = *(const uint4*)(whh + (768 + j * 128 + rg) * 256 +
                                        slice * 64 + hf * 32 + q * 8);
        *(uint4*)&S.w[(wv * 16 + j * 8 + hf * 4 + q) * 256 + ln * 4] = v;
      }

  const int t0 = ch * Tc;
  if (LAYER == 0) {
    for (int i = tid; i < Tc * 8; i += 512) {
      int dp = i / Tc, tt = i - dp * Tc;
      float v0 = P.x[(b * INCH + 2 * dp) * T_SEQ + t0 + tt];
      float v1 = P.x[(b * INCH + 2 * dp + 1) * T_SEQ + t0 + tt];
      uint32_t pv = (uint32_t)__half_as_ushort(__float2half(v0)) |
                    ((uint32_t)__half_as_ushort(__float2half(v1)) << 16);
      S.u.xb[tt * 8 + dp] = pv;
    }
  } else {
    for (int i = tid; i < OC * 256; i += 512) {
      int o = i >> 8, k = i & 255;
      S.u.h1.whd[o * 272 + k] = P.whd[i];
    }
    if (tid < OC) S.u.h1.bh[tid] = P.bhd[tid];
  }

  // Per-thread bias for rows j=2*slice, 2*slice+1 (pre-reduction add).
  float bA, bB;
  {
    const float* bs = (LAYER == 0) ? P.bs0 : P.bs1;
    bA = bs[rg + 256 * slice];
    bB = bs[rg + 128 + 256 * slice];
  }

  // Register-resident weights: rows j=0..5, 64 halves each (32 packed u32).
  uint32_t wr[6][32];
#pragma unroll
  for (int j = 0; j < 6; j++) {
    const uint4* p = (const uint4*)(whh + (rg + 128 * j) * 256 + slice * 64);
#pragma unroll
    for (int q = 0; q < 8; q++) {
      uint4 v = p[q];
      wr[j][4 * q] = v.x; wr[j][4 * q + 1] = v.y;
      wr[j][4 * q + 2] = v.z; wr[j][4 * q + 3] = v.w;
    }
  }
#pragma unroll
  for (int j = 0; j < 6; j++)
#pragma unroll
    for (int q = 0; q < 32; q++) PIN(wr[j][q]);

  uint32_t wx[8][2];
  if (LAYER == 0) {
#pragma unroll
    for (int j = 0; j < 8; j++) {
      const uint32_t* p = (const uint32_t*)(P.wi0 + (rg + 128 * j) * INCH + slice * 4);
      wx[j][0] = p[0]; wx[j][1] = p[1];
    }
#pragma unroll
    for (int j = 0; j < 8; j++) { PIN(wx[j][0]); PIN(wx[j][1]); }
  }

  // State: slice0 owns channel rg, slice1 owns channel rg+128.
  float* hs = (LAYER == 0) ? P.h0s : P.h1s;
  float* cs = (LAYER == 0) ? P.c0s : P.c1s;
  const int mych = rg + 128 * slice;  // valid for slice < 2
  float hMy = 0.f, cMy = 0.f;
  if (slice < 2) {
    if (ch != 0) { hMy = hs[b * 256 + mych]; cMy = cs[b * 256 + mych]; }
    S.hbuf[0][(mych >> 6) * 80 + (mych & 63)] = __float2half(hMy);
  }
  // xw prefetch (layer1): rows rg+256*slice, rg+128+256*slice at tt=0.
  float xwA = 0.f, xwB = 0.f;
  if (LAYER == 1) {
    const __half* base = P.xwr + (size_t)b * G4;
    xwA = __half2float(base[rg + 256 * slice]);
    xwB = __half2float(base[rg + 128 + 256 * slice]);
  }
  __syncthreads();

  for (int tt = 0; tt < Tc; ++tt) {
    const __half* hb = S.hbuf[tt & 1];
    float acc[8];
#pragma unroll
    for (int j = 0; j < 8; j++) acc[j] = 0.f;

#pragma unroll
    for (int hf = 0; hf < 2; ++hf) {
      uint32_t hh[16];
      const uint4* hp = (const uint4*)(hb + slice * 80 + hf * 32);
#pragma unroll
      for (int q = 0; q < 4; q++) {
        uint4 v = hp[q];
        hh[4 * q] = v.x; hh[4 * q + 1] = v.y; hh[4 * q + 2] = v.z; hh[4 * q + 3] = v.w;
      }
#pragma unroll
      for (int j = 0; j < 6; j++) {
        float a = acc[j];
#pragma unroll
        for (int q = 0; q < 16; q++) a = fdot2(wr[j][hf * 16 + q], hh[q], a);
        acc[j] = a;
      }
#pragma unroll
      for (int j = 0; j < 2; j++) {
        float a = acc[6 + j];
#pragma unroll
        for (int q = 0; q < 4; q++) {
          const uint4 v = *(const uint4*)&S.w[(wv * 16 + j * 8 + hf * 4 + q) * 256 + ln * 4];
          a = fdot2(v.x, hh[4 * q], a);
          a = fdot2(v.y, hh[4 * q + 1], a);
          a = fdot2(v.z, hh[4 * q + 2], a);
          a = fdot2(v.w, hh[4 * q + 3], a);
        }
        acc[6 + j] = a;
      }
    }
    if (LAYER == 0) {
      uint32_t xv0 = S.u.xb[tt * 8 + 2 * slice];
      uint32_t xv1 = S.u.xb[tt * 8 + 2 * slice + 1];
#pragma unroll
      for (int j = 0; j < 8; j++) {
        acc[j] = fdot2(wx[j][0], xv0, acc[j]);
        acc[j] = fdot2(wx[j][1], xv1, acc[j]);
      }
    }
    // Pre-reduction bias (+xw) add with LITERAL indices (no dynamic acc[]).
    float addA = bA, addB = bB;
    if (LAYER == 1) {
      addA += xwA; addB += xwB;
      if (tt + 1 < Tc) {
        const __half* base = P.xwr + ((size_t)(tt + 1) * NB + b) * G4;
        xwA = __half2float(base[rg + 256 * slice]);
        xwB = __half2float(base[rg + 128 + 256 * slice]);
      }
    }
    if (slice == 0)      { acc[0] += addA; acc[1] += addB; }
    else if (slice == 1) { acc[2] += addA; acc[3] += addB; }
    else if (slice == 2) { acc[4] += addA; acc[5] += addB; }
    else                 { acc[6] += addA; acc[7] += addB; }

    // Quad butterfly: every quad lane gets all 8 full sums (pure VALU DPP).
#pragma unroll
    for (int j = 0; j < 8; j++) acc[j] = qsum4(acc[j]);

    // State update, split across two lanes per quad.
    if (slice == 0) {
      float iv = sigf(acc[0]), fv = sigf(acc[2]);
      float gv = tanhf_fast(acc[4]), ov = sigf(acc[6]);
      cMy = fv * cMy + iv * gv;
      hMy = ov * tanhf_fast(cMy);
      __half h16 = __float2half(hMy);
      S.hbuf[(tt + 1) & 1][(rg >> 6) * 80 + (rg & 63)] = h16;
      if (LAYER == 0) {
        P.h1w[(size_t)(tt * NB + b) * 256 + rg] = h16;
      } else {
        float a = hMy > 0.f ? hMy : 0.01f * hMy;
        S.u.h1.abuf[tt & 1][(rg >> 5) * 40 + (rg & 31)] = __float2half(a);
      }
    } else if (slice == 1) {
      float iv = sigf(acc[1]), fv = sigf(acc[3]);
      float gv = tanhf_fast(acc[5]), ov = sigf(acc[7]);
      cMy = fv * cMy + iv * gv;
      hMy = ov * tanhf_fast(cMy);
      __half h16 = __float2half(hMy);
      const int chB = rg + 128;
      S.hbuf[(tt + 1) & 1][(chB >> 6) * 80 + (chB & 63)] = h16;
      if (LAYER == 0) {
        P.h1w[(size_t)(tt * NB + b) * 256 + chB] = h16;
      } else {
        float a = hMy > 0.f ? hMy : 0.01f * hMy;
        S.u.h1.abuf[tt & 1][(chB >> 5) * 40 + (chB & 31)] = __float2half(a);
      }
    }
    __syncthreads();

    // Head (layer1): 20 outputs x 8 lanes x 32 k. Reads abuf[tt&1]; next
    // overwrite of that buffer is 2 steps away behind an intervening barrier.
    if (LAYER == 1 && tid < OC * 8) {
      int o = tid >> 3, ks = tid & 7;
      const uint4* wp = (const uint4*)&S.u.h1.whd[o * 272 + ks * 32];
      const uint4* ap = (const uint4*)&S.u.h1.abuf[tt & 1][ks * 40];
      float a = 0.f;
#pragma unroll
      for (int q = 0; q < 4; q++) {
        uint4 w4 = wp[q];
        uint4 a4 = ap[q];
        a = fdot2(w4.x, a4.x, a);
        a = fdot2(w4.y, a4.y, a);
        a = fdot2(w4.z, a4.z, a);
        a = fdot2(w4.w, a4.w, a);
      }
      a += __shfl_xor(a, 1);
      a += __shfl_xor(a, 2);
      a += __shfl_xor(a, 4);
      if (ks == 0) P.y[(b * OC + o) * T_SEQ + t0 + tt] = a + S.u.h1.bh[o];
    }
  }
  if (slice < 2) {
    hs[b * 256 + mych] = hMy;
    cs[b * 256 + mych] = cMy;
  }
}

// ---------------------------------------------------------------------------
// GEMM role: xw1[tb, g] = sum_k h1[tb,k] * Wih1[g,k], f16 MFMA, f16 out.
// ---------------------------------------------------------------------------
__device__ void role_gemm(SmemG& S, int chG, const Params& P) {
  if (chG < 0 || chG >= P.nch) return;
  const int bid = blockIdx.x - 128;
  const int nt = bid & 15, mt = bid >> 4;
  const int tb0 = mt * 128, g0 = nt * 64;
  const int tid = threadIdx.x, lane = tid & 63, w = tid >> 6;
  const int wm = w & 3, wn = w >> 2;

  f32x4 cacc[2][2] = {};
  for (int kk = 0; kk < 256; kk += 32) {
    __syncthreads();
    {
      int row = tid >> 2, q = tid & 3;
      const uint4* src = (const uint4*)(P.h1r + (tb0 + row) * 256 + kk + q * 8);
      *(uint4*)&S.a[row * 40 + q * 8] = *src;
    }
    if (tid < 256) {
      int row = tid >> 2, q = tid & 3;
      const uint4* src = (const uint4*)(P.wi1 + (g0 + row) * 256 + kk + q * 8);
      *(uint4*)&S.b[row * 40 + q * 8] = *src;
    }
    __syncthreads();
    f16x8 af[2], bf[2];
#pragma unroll
    for (int mi = 0; mi < 2; mi++)
      af[mi] = *(const f16x8*)&S.a[(wm * 32 + mi * 16 + (lane & 15)) * 40 + (lane >> 4) * 8];
#pragma unroll
    for (int ni = 0; ni < 2; ni++)
      bf[ni] = *(const f16x8*)&S.b[(wn * 32 + ni * 16 + (lane & 15)) * 40 + (lane >> 4) * 8];
#pragma unroll
    for (int mi = 0; mi < 2; mi++)
#pragma unroll
      for (int ni = 0; ni < 2; ni++)
        cacc[mi][ni] = __builtin_amdgcn_mfma_f32_16x16x32_f16(af[mi], bf[ni], cacc[mi][ni], 0, 0, 0);
  }
#pragma unroll
  for (int mi = 0; mi < 2; mi++)
#pragma unroll
    for (int ni = 0; ni < 2; ni++) {
      int m = wm * 32 + mi * 16 + (lane >> 4) * 4;
      int n = g0 + wn * 32 + ni * 16 + (lane & 15);
#pragma unroll
      for (int r = 0; r < 4; r++)
        P.xww[(size_t)(tb0 + m + r) * G4 + n] = __float2half(cacc[mi][ni][r]);
    }
}

__global__ __launch_bounds__(512)
__attribute__((amdgpu_waves_per_eu(2, 2)))
void fused_kernel(Params P) {
  __shared__ Smem S;
  int bid = blockIdx.x;
  if (bid < 64)        role_rec<0>(S.r, P.L, P, bid);
  else if (bid < 128)  role_rec<1>(S.r, P.L - 2, P, bid - 64);
  else                 role_gemm(S.g, P.L - 1, P);
}

// ---------------------------------------------------------------------------
__global__ void prep_kernel(const float* Wih0, const float* Whh0,
                            const float* bih0, const float* bhh0,
                            const float* Wih1, const float* Whh1,
                            const float* bih1, const float* bhh1,
                            const float* Whead, const float* bhead,
                            __half* wh0, __half* wh1, __half* wi1, __half* wi0,
                            __half* whd, float* bs0, float* bs1, float* bhd) {
  int i = blockIdx.x * blockDim.x + threadIdx.x;
  if (i < G4 * HID) {
    wh0[i] = __float2half(Whh0[i]);
    wh1[i] = __float2half(Whh1[i]);
    wi1[i] = __float2half(Wih1[i]);
  }
  if (i < G4 * INCH) wi0[i] = __float2half(Wih0[i]);
  if (i < OC * HID)  whd[i] = __float2half(Whead[i]);
  if (i < G4) { bs0[i] = bih0[i] + bhh0[i]; bs1[i] = bih1[i] + bhh1[i]; }
  if (i < OC) bhd[i] = bhead[i];
}

// ---------------------------------------------------------------------------
extern "C" void kernel_launch(void* const* d_in, const int* in_sizes, int n_in,
                              void* d_out, int out_size, void* d_ws, size_t ws_size,
                              hipStream_t stream) {
  const float* x     = (const float*)d_in[0];
  const float* Wih0  = (const float*)d_in[1];
  const float* Whh0  = (const float*)d_in[2];
  const float* bih0  = (const float*)d_in[3];
  const float* bhh0  = (const float*)d_in[4];
  const float* Wih1  = (const float*)d_in[5];
  const float* Whh1  = (const float*)d_in[6];
  const float* bih1  = (const float*)d_in[7];
  const float* bhh1  = (const float*)d_in[8];
  const float* Whead = (const float*)d_in[9];
  const float* bhead = (const float*)d_in[10];
  float* y = (float*)d_out;

  char* ws = (char*)d_ws;
  size_t cur = 0;
  auto alloc = [&](size_t sz) -> char* {
    char* p = ws + cur;
    cur = (cur + sz + 255) & ~(size_t)255;
    return p;
  };
  __half* wh0 = (__half*)alloc(G4 * HID * 2);
  __half* wh1 = (__half*)alloc(G4 * HID * 2);
  __half* wi1 = (__half*)alloc(G4 * HID * 2);
  __half* wi0 = (__half*)alloc(G4 * INCH * 2);
  __half* whd = (__half*)alloc(OC * HID * 2);
  float* bs0 = (float*)alloc(G4 * 4);
  float* bs1 = (float*)alloc(G4 * 4);
  float* bhd = (float*)alloc(OC * 4);
  float* h0s = (float*)alloc(NB * HID * 4);
  float* c0s = (float*)alloc(NB * HID * 4);
  float* h1s = (float*)alloc(NB * HID * 4);
  float* c1s = (float*)alloc(NB * HID * 4);

  const int Tc = TCH;
  __half* h1buf[2];
  __half* xwbuf[2];
  h1buf[0] = (__half*)alloc((size_t)Tc * NB * HID * 2);
  h1buf[1] = (__half*)alloc((size_t)Tc * NB * HID * 2);
  xwbuf[0] = (__half*)alloc((size_t)Tc * NB * G4 * 2);
  xwbuf[1] = (__half*)alloc((size_t)Tc * NB * G4 * 2);

  const int nch = T_SEQ / Tc;

  prep_kernel<<<(G4 * HID + 255) / 256, 256, 0, stream>>>(
      Wih0, Whh0, bih0, bhh0, Wih1, Whh1, bih1, bhh1, Whead, bhead,
      wh0, wh1, wi1, wi0, whd, bs0, bs1, bhd);

  const int ngemm = Tc * 8;
  for (int L = 0; L < nch + 2; ++L) {
    Params P;
    P.x = x;
    P.wh0 = wh0; P.wh1 = wh1; P.wi0 = wi0; P.wi1 = wi1; P.whd = whd;
    P.bs0 = bs0; P.bs1 = bs1; P.bhd = bhd;
    P.h0s = h0s; P.c0s = c0s; P.h1s = h1s; P.c1s = c1s;
    P.h1w = h1buf[L & 1];
    P.h1r = h1buf[(L + 1) & 1];
    P.xww = xwbuf[(L + 1) & 1];
    P.xwr = xwbuf[L & 1];
    P.y = y;
    P.L = L; P.Tc = Tc; P.nch = nch;
    fused_kernel<<<128 + ngemm, 512, 0, stream>>>(P);
  }
}

// Round 5
// 16413.106 us; speedup vs baseline: 1.6588x; 1.5435x over previous
//
#include <hip/hip_runtime.h>
#include <hip/hip_fp16.h>
#include <stdint.h>

// ---------------------------------------------------------------------------
// SequentialEMGPoseLSTM: 2-layer LSTM (H=256, B=64, T=4096) + LeakyReLU+Linear
//
// R5: revert to R2 structure (proven 10.87ms) + restructure recurrent blocks
// to 1024 threads / k-split 8 so the 6 register-resident weight rows need only
// 96 VGPRs -> hot set fits the compiler's 128-arch-VGPR budget (every prior
// round showed VGPR_Count=128 with weights silently homed in AGPRs behind
// v_accvgpr_read, doubling VALU issue). __launch_bounds__(1024,4) matches the
// allocator's natural 4-waves/EU target. 16 waves/block also hides LDS/barrier
// latency better. Reduction = DPP xor1+xor2 and ds_swizzle xor4.
// Keep from R2: padded-264 o-gate LDS layout, fp32 xw, Tc=256, 1 barrier/step.
// ---------------------------------------------------------------------------

#define T_SEQ 4096
#define NB    64
#define HID   256
#define G4    1024
#define INCH  16
#define OC    20
#define TCH   256

typedef _Float16 h2v   __attribute__((ext_vector_type(2)));
typedef _Float16 f16x8 __attribute__((ext_vector_type(8)));
typedef float    f32x4 __attribute__((ext_vector_type(4)));

__device__ __forceinline__ float fdot2(uint32_t a, uint32_t b, float c) {
  return __builtin_amdgcn_fdot2(__builtin_bit_cast(h2v, a),
                                __builtin_bit_cast(h2v, b), c, false);
}
__device__ __forceinline__ float sigf(float x) {
  x = fminf(fmaxf(x, -30.f), 30.f);
  return 1.f / (1.f + __expf(-x));
}
__device__ __forceinline__ float tanhf_fast(float x) {
  x = fminf(fmaxf(x, -15.f), 15.f);
  float e = __expf(-2.f * x);
  return (1.f - e) / (1.f + e);
}
// Quad butterfly (pure VALU DPP): all 4 lanes of each quad get the quad sum.
__device__ __forceinline__ float qsum4(float x) {
  int t = __builtin_amdgcn_mov_dpp(__float_as_int(x), 0xB1, 0xF, 0xF, true);
  x += __int_as_float(t);
  t = __builtin_amdgcn_mov_dpp(__float_as_int(x), 0x4E, 0xF, 0xF, true);
  return x + __int_as_float(t);
}
// xor-4 lane exchange via ds_swizzle BitMode: offset=(4<<10)|0x1F.
__device__ __forceinline__ float xadd4(float x) {
  int t = __builtin_amdgcn_ds_swizzle(__float_as_int(x), 0x101F);
  return x + __int_as_float(t);
}

#define PIN(x) asm volatile("" : "+v"(x))

// LDS layout (recurrent):
//  w   : o-gate rows 768..1023 of Whh, row-major with stride 264 halves
//        (R2-proven padding).
//  hbuf: 2 buffers x 8 chunks x 40 halves (chunk = 32 h values + pad).
//        Per b128 read instruction the 8 slice-spans are disjoint 4-dword
//        bank ranges: start banks {0,20,8,28,16,4,24,12}+const.
//  abuf: 2 buffers x 8 chunks x 40 halves (same property).
struct SmemR {
  __half w[256 * 264];        // 135168 B
  __half hbuf[2][8 * 40];     // 1280 B
  union {
    uint32_t xb[TCH * 8];     // layer0: packed x pairs [tt][dp]
    struct {
      __half abuf[2][8 * 40];
      __half whd[20 * 264];
      float  bh[20];
    } h1;
  } u;
};
struct SmemG {
  __half a[128 * 40];
  __half b[64 * 40];
};
union Smem { SmemR r; SmemG g; };

struct Params {
  const float* x;
  const __half *wh0, *wh1, *wi0, *wi1, *whd;
  const float  *bs0, *bs1, *bhd;
  float *h0s, *c0s, *h1s, *c1s;
  __half* h1w; const __half* h1r;
  float* xww;  const float* xwr;
  float* y;
  int L, Tc, nch;
};

// ---------------------------------------------------------------------------
// Recurrent role: one block == one batch chain. 1024 threads, 16 waves.
// slice = tid&7 covers k in [32*slice, 32*slice+32); rg = tid>>3 (0..127).
// Thread handles gate rows r = rg + 128*j, j=0..7 (j<6 reg: 96 VGPRs,
// j=6,7 from LDS). Row rg+128j: j even -> gate j/2 of channel rg; j odd ->
// gate j/2 of channel rg+128. After xor1/2/4 reduction every lane has all 8
// sums; slice0 updates channel rg, slice1 channel rg+128.
// ---------------------------------------------------------------------------
template <int LAYER>
__device__ void role_rec(SmemR& S, int ch, const Params& P, int b) {
  if (ch < 0 || ch >= P.nch) return;
  const int tid   = threadIdx.x;
  const int slice = tid & 7;
  const int rg    = tid >> 3;
  const int Tc    = P.Tc;
  const __half* whh = (LAYER == 0) ? P.wh0 : P.wh1;

  // Stage o-gate weight rows 768..1023 (8192 uint4) into 264-stride layout.
  for (int i = tid; i < 8192; i += 1024) {
    int R = i >> 5, oct = i & 31;
    *(uint4*)&S.w[R * 264 + oct * 8] =
        *((const uint4*)(whh + (768 + R) * 256) + oct);
  }

  const int t0 = ch * Tc;
  if (LAYER == 0) {
    for (int i = tid; i < Tc * 8; i += 1024) {
      int dp = i / Tc, tt = i - dp * Tc;
      float v0 = P.x[(b * INCH + 2 * dp) * T_SEQ + t0 + tt];
      float v1 = P.x[(b * INCH + 2 * dp + 1) * T_SEQ + t0 + tt];
      uint32_t pv = (uint32_t)__half_as_ushort(__float2half(v0)) |
                    ((uint32_t)__half_as_ushort(__float2half(v1)) << 16);
      S.u.xb[tt * 8 + dp] = pv;
    }
  } else {
    for (int i = tid; i < OC * 256; i += 1024) {
      int o = i >> 8, k = i & 255;
      S.u.h1.whd[o * 264 + k] = P.whd[i];
    }
    if (tid < OC) S.u.h1.bh[tid] = P.bhd[tid];
  }

  // Register-resident weights: rows j=0..5, 32 halves each (16 packed u32).
  uint32_t wr[6][16];
#pragma unroll
  for (int j = 0; j < 6; j++) {
    const uint4* p = (const uint4*)(whh + (rg + 128 * j) * 256 + slice * 32);
#pragma unroll
    for (int q = 0; q < 4; q++) {
      uint4 v = p[q];
      wr[j][4 * q] = v.x; wr[j][4 * q + 1] = v.y;
      wr[j][4 * q + 2] = v.z; wr[j][4 * q + 3] = v.w;
    }
  }
#pragma unroll
  for (int j = 0; j < 6; j++)
#pragma unroll
    for (int q = 0; q < 16; q++) PIN(wr[j][q]);

  // Layer0 input weights: dims (2*slice, 2*slice+1) of each row: 1 u32/row.
  uint32_t wx[8];
  if (LAYER == 0) {
#pragma unroll
    for (int j = 0; j < 8; j++)
      wx[j] = *(const uint32_t*)(P.wi0 + (rg + 128 * j) * INCH + slice * 2);
#pragma unroll
    for (int j = 0; j < 8; j++) PIN(wx[j]);
  }

  // State + bias: slice0 owns channel rg, slice1 owns channel rg+128.
  float* hs = (LAYER == 0) ? P.h0s : P.h1s;
  float* cs = (LAYER == 0) ? P.c0s : P.c1s;
  const int mych = rg + 128 * (slice & 1);
  float hMy = 0.f, cMy = 0.f;
  float bI = 0.f, bF = 0.f, bG = 0.f, bO = 0.f;
  if (slice < 2) {
    const float* bs = (LAYER == 0) ? P.bs0 : P.bs1;
    bI = bs[mych];
    bF = bs[mych + 256];
    bG = bs[mych + 512];
    bO = bs[mych + 768];
    if (ch != 0) { hMy = hs[b * 256 + mych]; cMy = cs[b * 256 + mych]; }
    S.hbuf[0][(mych >> 5) * 40 + (mych & 31)] = __float2half(hMy);
  }
  // xw prefetch (layer1): 4 gate rows of channel mych at tt=0.
  float xwI = 0.f, xwF = 0.f, xwG = 0.f, xwO = 0.f;
  if (LAYER == 1 && slice < 2) {
    const float* base = P.xwr + (size_t)b * G4 + mych;
    xwI = base[0]; xwF = base[256]; xwG = base[512]; xwO = base[768];
  }
  __syncthreads();

  for (int tt = 0; tt < Tc; ++tt) {
    const __half* hb = S.hbuf[tt & 1];
    float acc[8];
#pragma unroll
    for (int j = 0; j < 8; j++) acc[j] = 0.f;

#pragma unroll
    for (int hf = 0; hf < 2; ++hf) {
      uint32_t hh[8];
      const uint4* hp = (const uint4*)(hb + slice * 40 + hf * 16);
#pragma unroll
      for (int q = 0; q < 2; q++) {
        uint4 v = hp[q];
        hh[4 * q] = v.x; hh[4 * q + 1] = v.y;
        hh[4 * q + 2] = v.z; hh[4 * q + 3] = v.w;
      }
#pragma unroll
      for (int j = 0; j < 6; j++) {
        float a = acc[j];
#pragma unroll
        for (int q = 0; q < 8; q++) a = fdot2(wr[j][hf * 8 + q], hh[q], a);
        acc[j] = a;
      }
#pragma unroll
      for (int jj = 0; jj < 2; jj++) {
        const uint4* wp =
            (const uint4*)&S.w[(jj * 128 + rg) * 264 + slice * 32 + hf * 16];
        float a = acc[6 + jj];
#pragma unroll
        for (int q = 0; q < 2; q++) {
          uint4 v = wp[q];
          a = fdot2(v.x, hh[4 * q], a);
          a = fdot2(v.y, hh[4 * q + 1], a);
          a = fdot2(v.z, hh[4 * q + 2], a);
          a = fdot2(v.w, hh[4 * q + 3], a);
        }
        acc[6 + jj] = a;
      }
    }
    if (LAYER == 0) {
      uint32_t xv = S.u.xb[tt * 8 + slice];
#pragma unroll
      for (int j = 0; j < 8; j++) acc[j] = fdot2(wx[j], xv, acc[j]);
    }

    // Reduce over 8 k-slices: DPP quad butterfly + ds_swizzle xor4.
#pragma unroll
    for (int j = 0; j < 8; j++) acc[j] = xadd4(qsum4(acc[j]));

    // State update: slice0 -> channel rg (even j), slice1 -> rg+128 (odd j).
    if (slice < 2) {
      float gI, gF, gG, gO;
      if (slice == 0) { gI = acc[0]; gF = acc[2]; gG = acc[4]; gO = acc[6]; }
      else            { gI = acc[1]; gF = acc[3]; gG = acc[5]; gO = acc[7]; }
      gI += bI; gF += bF; gG += bG; gO += bO;
      if (LAYER == 1) {
        gI += xwI; gF += xwF; gG += xwG; gO += xwO;
        if (tt + 1 < Tc) {
          const float* base = P.xwr + ((size_t)(tt + 1) * NB + b) * G4 + mych;
          xwI = base[0]; xwF = base[256]; xwG = base[512]; xwO = base[768];
        }
      }
      float iv = sigf(gI), fv = sigf(gF);
      float gv = tanhf_fast(gG), ov = sigf(gO);
      cMy = fv * cMy + iv * gv;
      hMy = ov * tanhf_fast(cMy);
      __half h16 = __float2half(hMy);
      S.hbuf[(tt + 1) & 1][(mych >> 5) * 40 + (mych & 31)] = h16;
      if (LAYER == 0) {
        P.h1w[(size_t)(tt * NB + b) * 256 + mych] = h16;
      } else {
        float a = hMy > 0.f ? hMy : 0.01f * hMy;
        S.u.h1.abuf[tt & 1][(mych >> 5) * 40 + (mych & 31)] = __float2half(a);
      }
    }
    __syncthreads();

    // Head (layer1): 20 outputs x 8 lanes x 32 k. Reads abuf[tt&1]; its next
    // overwrite is 2 steps away behind an intervening barrier.
    if (LAYER == 1 && tid < OC * 8) {
      int o = tid >> 3, ks = tid & 7;
      const uint4* wp = (const uint4*)&S.u.h1.whd[o * 264 + ks * 32];
      const uint4* ap = (const uint4*)&S.u.h1.abuf[tt & 1][ks * 40];
      float a = 0.f;
#pragma unroll
      for (int q = 0; q < 4; q++) {
        uint4 w4 = wp[q];
        uint4 a4 = ap[q];
        a = fdot2(w4.x, a4.x, a);
        a = fdot2(w4.y, a4.y, a);
        a = fdot2(w4.z, a4.z, a);
        a = fdot2(w4.w, a4.w, a);
      }
      a += __shfl_xor(a, 1);
      a += __shfl_xor(a, 2);
      a += __shfl_xor(a, 4);
      if (ks == 0) P.y[(b * OC + o) * T_SEQ + t0 + tt] = a + S.u.h1.bh[o];
    }
  }
  if (slice < 2) {
    hs[b * 256 + mych] = hMy;
    cs[b * 256 + mych] = cMy;
  }
}

// ---------------------------------------------------------------------------
// GEMM role: xw1[tb, g] = sum_k h1[tb,k] * Wih1[g,k], f16 MFMA, fp32 out.
// 1024-thread block; first 512 threads do the work (tile 128x64), barriers
// are hit by all waves (tid<512 is wave-uniform).
// ---------------------------------------------------------------------------
__device__ void role_gemm(SmemG& S, int chG, const Params& P) {
  if (chG < 0 || chG >= P.nch) return;
  const int bid = blockIdx.x - 128;
  const int nt = bid & 15, mt = bid >> 4;
  const int tb0 = mt * 128, g0 = nt * 64;
  const int tid = threadIdx.x, lane = tid & 63, w = tid >> 6;
  const int wm = w & 3, wn = w >> 2;
  const bool act = tid < 512;

  f32x4 cacc[2][2] = {};
  for (int kk = 0; kk < 256; kk += 32) {
    __syncthreads();
    if (act) {
      int row = tid >> 2, q = tid & 3;
      *(uint4*)&S.a[row * 40 + q * 8] =
          *(const uint4*)(P.h1r + (tb0 + row) * 256 + kk + q * 8);
      if (tid < 256)
        *(uint4*)&S.b[row * 40 + q * 8] =
            *(const uint4*)(P.wi1 + (g0 + row) * 256 + kk + q * 8);
    }
    __syncthreads();
    if (act) {
      f16x8 af[2], bf[2];
#pragma unroll
      for (int mi = 0; mi < 2; mi++)
        af[mi] = *(const f16x8*)&S.a[(wm * 32 + mi * 16 + (lane & 15)) * 40 + (lane >> 4) * 8];
#pragma unroll
      for (int ni = 0; ni < 2; ni++)
        bf[ni] = *(const f16x8*)&S.b[(wn * 32 + ni * 16 + (lane & 15)) * 40 + (lane >> 4) * 8];
#pragma unroll
      for (int mi = 0; mi < 2; mi++)
#pragma unroll
        for (int ni = 0; ni < 2; ni++)
          cacc[mi][ni] = __builtin_amdgcn_mfma_f32_16x16x32_f16(af[mi], bf[ni], cacc[mi][ni], 0, 0, 0);
    }
  }
  if (act) {
#pragma unroll
    for (int mi = 0; mi < 2; mi++)
#pragma unroll
      for (int ni = 0; ni < 2; ni++) {
        int m = wm * 32 + mi * 16 + (lane >> 4) * 4;
        int n = g0 + wn * 32 + ni * 16 + (lane & 15);
#pragma unroll
        for (int r = 0; r < 4; r++)
          P.xww[(size_t)(tb0 + m + r) * G4 + n] = cacc[mi][ni][r];
      }
  }
}

__global__ __launch_bounds__(1024, 4) void fused_kernel(Params P) {
  __shared__ Smem S;
  int bid = blockIdx.x;
  if (bid < 64)        role_rec<0>(S.r, P.L, P, bid);
  else if (bid < 128)  role_rec<1>(S.r, P.L - 2, P, bid - 64);
  else                 role_gemm(S.g, P.L - 1, P);
}

// ---------------------------------------------------------------------------
__global__ void prep_kernel(const float* Wih0, const float* Whh0,
                            const float* bih0, const float* bhh0,
                            const float* Wih1, const float* Whh1,
                            const float* bih1, const float* bhh1,
                            const float* Whead, const float* bhead,
                            __half* wh0, __half* wh1, __half* wi1, __half* wi0,
                            __half* whd, float* bs0, float* bs1, float* bhd) {
  int i = blockIdx.x * blockDim.x + threadIdx.x;
  if (i < G4 * HID) {
    wh0[i] = __float2half(Whh0[i]);
    wh1[i] = __float2half(Whh1[i]);
    wi1[i] = __float2half(Wih1[i]);
  }
  if (i < G4 * INCH) wi0[i] = __float2half(Wih0[i]);
  if (i < OC * HID)  whd[i] = __float2half(Whead[i]);
  if (i < G4) { bs0[i] = bih0[i] + bhh0[i]; bs1[i] = bih1[i] + bhh1[i]; }
  if (i < OC) bhd[i] = bhead[i];
}

// ---------------------------------------------------------------------------
extern "C" void kernel_launch(void* const* d_in, const int* in_sizes, int n_in,
                              void* d_out, int out_size, void* d_ws, size_t ws_size,
                              hipStream_t stream) {
  const float* x     = (const float*)d_in[0];
  const float* Wih0  = (const float*)d_in[1];
  const float* Whh0  = (const float*)d_in[2];
  const float* bih0  = (const float*)d_in[3];
  const float* bhh0  = (const float*)d_in[4];
  const float* Wih1  = (const float*)d_in[5];
  const float* Whh1  = (const float*)d_in[6];
  const float* bih1  = (const float*)d_in[7];
  const float* bhh1  = (const float*)d_in[8];
  const float* Whead = (const float*)d_in[9];
  const float* bhead = (const float*)d_in[10];
  float* y = (float*)d_out;

  char* ws = (char*)d_ws;
  size_t cur = 0;
  auto alloc = [&](size_t sz) -> char* {
    char* p = ws + cur;
    cur = (cur + sz + 255) & ~(size_t)255;
    return p;
  };
  __half* wh0 = (__half*)alloc(G4 * HID * 2);
  __half* wh1 = (__half*)alloc(G4 * HID * 2);
  __half* wi1 = (__half*)alloc(G4 * HID * 2);
  __half* wi0 = (__half*)alloc(G4 * INCH * 2);
  __half* whd = (__half*)alloc(OC * HID * 2);
  float* bs0 = (float*)alloc(G4 * 4);
  float* bs1 = (float*)alloc(G4 * 4);
  float* bhd = (float*)alloc(OC * 4);
  float* h0s = (float*)alloc(NB * HID * 4);
  float* c0s = (float*)alloc(NB * HID * 4);
  float* h1s = (float*)alloc(NB * HID * 4);
  float* c1s = (float*)alloc(NB * HID * 4);

  const int Tc = TCH;
  __half* h1buf[2];
  float* xwbuf[2];
  h1buf[0] = (__half*)alloc((size_t)Tc * NB * HID * 2);
  h1buf[1] = (__half*)alloc((size_t)Tc * NB * HID * 2);
  xwbuf[0] = (float*)alloc((size_t)Tc * NB * G4 * 4);
  xwbuf[1] = (float*)alloc((size_t)Tc * NB * G4 * 4);

  const int nch = T_SEQ / Tc;

  prep_kernel<<<(G4 * HID + 255) / 256, 256, 0, stream>>>(
      Wih0, Whh0, bih0, bhh0, Wih1, Whh1, bih1, bhh1, Whead, bhead,
      wh0, wh1, wi1, wi0, whd, bs0, bs1, bhd);

  const int ngemm = Tc * 8;
  for (int L = 0; L < nch + 2; ++L) {
    Params P;
    P.x = x;
    P.wh0 = wh0; P.wh1 = wh1; P.wi0 = wi0; P.wi1 = wi1; P.whd = whd;
    P.bs0 = bs0; P.bs1 = bs1; P.bhd = bhd;
    P.h0s = h0s; P.c0s = c0s; P.h1s = h1s; P.c1s = c1s;
    P.h1w = h1buf[L & 1];
    P.h1r = h1buf[(L + 1) & 1];
    P.xww = xwbuf[(L + 1) & 1];
    P.xwr = xwbuf[L & 1];
    P.y = y;
    P.L = L; P.Tc = Tc; P.nch = nch;
    fused_kernel<<<128 + ngemm, 1024, 0, stream>>>(P);
  }
}

// Round 6
// 11033.417 us; speedup vs baseline: 2.4676x; 1.4876x over previous
//
#include <hip/hip_runtime.h>
#include <hip/hip_fp16.h>
#include <stdint.h>

// ---------------------------------------------------------------------------
// SequentialEMGPoseLSTM: 2-layer LSTM (H=256, B=64, T=4096) + LeakyReLU+Linear
//
// R6: MFMA-based recurrence. R1-R5 post-mortem: the allocator always homes
// large per-thread arrays in AGPRs; fdot2 (VALU) then pays v_accvgpr_read per
// use (VGPR_Count 64..128 every round). MFMA reads A/B/C from AGPRs natively,
// so the weight-resident design becomes free:
//  - block = 4 chains, 512 thr; gates = Whh*H via mfma_f32_16x16x32_f16
//    (B cols = 4 chains replicated x4). K-reduction inside MFMA: no shuffles.
//  - Whh: 6/8 K-chunks persistent register A-frags (192 regs, AGPR-legal),
//    2/8 streamed from LDS (128 KB/step, lane-interleaved, conflict-free).
//  - activations: 2 (channel,chain) updates/lane via the x4 col redundancy,
//    literal-index extracts only (R3 scratch lesson).
//  - xw = Wih*input (+bias) precomputed per chunk by GEMM roles (f16);
//    REC adds its 8 values post-K-loop (latency hidden).
//  - head: 2 MFMA tiles on waves 0/1, one-step-delayed a-buffer -> still
//    ONE barrier per step.
// ---------------------------------------------------------------------------

#define T_SEQ 4096
#define NB    64
#define HID   256
#define G4    1024
#define INCH  16
#define OC    20

typedef _Float16 f16x2 __attribute__((ext_vector_type(2)));
typedef _Float16 f16x4 __attribute__((ext_vector_type(4)));
typedef _Float16 f16x8 __attribute__((ext_vector_type(8)));
typedef float    f32x4 __attribute__((ext_vector_type(4)));

#define MFMA16(A, B, C) __builtin_amdgcn_mfma_f32_16x16x32_f16((A), (B), (C), 0, 0, 0)

__device__ __forceinline__ float sigf(float x) {
  return 1.f / (1.f + __expf(-x));      // x=-inf -> 0, +inf -> 1 (no NaN)
}
__device__ __forceinline__ float tanhnf(float x) {
  return 1.f - 2.f / (1.f + __expf(2.f * x));  // +inf->1, -inf->-1 (no NaN)
}

// REC LDS: ldsA = streamed Whh chunks 6,7 (frag-major, lane*16B interleave).
// hbuf/abuf: [2 parity][4 chains x 272 halves] (544B chain stride: 16B-aligned,
// chains land on disjoint bank quads).
struct SmemR {
  _Float16 ldsA[65536];     // 131072 B: 8 waves x 16 frags x 512 halves
  _Float16 headA[8192];     // 16384 B: 16 frags (head A, rows padded to 32)
  _Float16 hbuf[2][1088];   // 4352 B
  _Float16 abuf[2][1088];   // 4352 B
};
struct SmemG0 { _Float16 xs[64 * 40]; };
union Smem { SmemR r; SmemG0 g0; };

struct Params {
  const float* x;
  const _Float16 *wh0, *wh1, *wi0p, *wi1, *whd;
  const float *bs0, *bs1, *bhd;
  float *h0s, *c0s, *h1s, *c1s;
  _Float16* h1w; const _Float16* h1r;
  _Float16* xw0w; const _Float16* xw0r;
  _Float16* xw1w; const _Float16* xw1r;
  float* y;
  int L, Tc, nch;
};

// ---------------------------------------------------------------------------
// Recurrent role. Wave wv owns channels wv*32..wv*32+31: 8 M-tiles
// ti = g*2 + hh -> rows g*256 + wv*32 + hh*16. Lane l: lcol=l&15 (A-row /
// D-col), kg=l>>4 (k-group / D-rowgrp), chain=l&3.
// ---------------------------------------------------------------------------
template <int LAYER>
__device__ void role_rec(SmemR& S, int chunk, const Params& P, int grp) {
  if (chunk < 0 || chunk >= P.nch) return;
  const int tid = threadIdx.x;
  const int wv = tid >> 6;
  const int l = tid & 63;
  const int lcol = l & 15;
  const int kg = l >> 4;
  const int chain = l & 3;
  const int Tc = P.Tc;
  const _Float16* whh = (LAYER == 0) ? P.wh0 : P.wh1;
  const _Float16* xwb = (LAYER == 0) ? P.xw0r : P.xw1r;

  // Stage LDS A-frags (chunks 6,7): lane-interleaved, conflict-free.
#pragma unroll
  for (int ti = 0; ti < 8; ti++) {
    int rowbase = (ti >> 1) * 256 + wv * 32 + (ti & 1) * 16;
#pragma unroll
    for (int cc = 6; cc < 8; cc++) {
      f16x8 v = *(const f16x8*)(whh + (rowbase + lcol) * 256 + cc * 32 + kg * 8);
      *(f16x8*)&S.ldsA[wv * 8192 + (ti * 2 + (cc - 6)) * 512 + l * 8] = v;
    }
  }
  if (LAYER == 1) {
    // Head A-frags: 16 frags (th 0..1 x cc 0..7); wave wv stages wv, wv+8.
#pragma unroll
    for (int fh = 0; fh < 2; fh++) {
      int f = wv + fh * 8;
      int th = f >> 3, cc = f & 7;
      int row = th * 16 + lcol;
      f16x8 v = {0, 0, 0, 0, 0, 0, 0, 0};
      if (row < OC) v = *(const f16x8*)(P.whd + row * 256 + cc * 32 + kg * 8);
      *(f16x8*)&S.headA[f * 512 + l * 8] = v;
    }
  }

  // Persistent register A-frags: chunks 0..5 x 8 tiles (192 regs; AGPR-ok).
  f16x8 wA[6][8];
#pragma unroll
  for (int cc = 0; cc < 6; cc++)
#pragma unroll
    for (int ti = 0; ti < 8; ti++) {
      int rowbase = (ti >> 1) * 256 + wv * 32 + (ti & 1) * 16;
      wA[cc][ti] = *(const f16x8*)(whh + (rowbase + lcol) * 256 + cc * 32 + kg * 8);
    }

  // Lane's activation assignment: hh = (l>>3)&1, rlo = ((l>>2)&1)*2.
  const int hh = (l >> 3) & 1;
  const int rlo = ((l >> 2) & 1) * 2;
  const int rg4x4 = kg * 4;
  const int ch0 = wv * 32 + hh * 16 + rg4x4 + rlo;  // handles ch0, ch0+1
  const int bglob = grp * 4 + chain;

  float* hs = (LAYER == 0) ? P.h0s : P.h1s;
  float* cs = (LAYER == 0) ? P.c0s : P.c1s;
  float c0 = 0.f, c1 = 0.f, h0v = 0.f, h1v = 0.f;
  if (chunk != 0) {
    c0 = cs[bglob * HID + ch0];  c1 = cs[bglob * HID + ch0 + 1];
    h0v = hs[bglob * HID + ch0]; h1v = hs[bglob * HID + ch0 + 1];
  }
  *(f16x2*)&S.hbuf[0][chain * 272 + ch0] = (f16x2){(_Float16)h0v, (_Float16)h1v};

  float hb0 = 0.f, hb1 = 0.f, hb2 = 0.f, hb3 = 0.f;
  if (LAYER == 1 && wv < 2) {
    int ob = wv * 16 + rg4x4;
    if (ob + 0 < OC) hb0 = P.bhd[ob + 0];
    if (ob + 1 < OC) hb1 = P.bhd[ob + 1];
    if (ob + 2 < OC) hb2 = P.bhd[ob + 2];
    if (ob + 3 < OC) hb3 = P.bhd[ob + 3];
  }
  __syncthreads();

  for (int tt = 0; tt <= Tc; ++tt) {
    f32x4 cacc[8];
    uint32_t xwg[4];
    if (tt < Tc) {
      // xw loads (post-loop add; latency hides behind the MFMA K-loop).
      const _Float16* xp = xwb + ((size_t)tt * NB + bglob) * G4 + ch0;
#pragma unroll
      for (int g = 0; g < 4; g++) xwg[g] = *(const uint32_t*)(xp + g * 256);
#pragma unroll
      for (int ti = 0; ti < 8; ti++) cacc[ti] = (f32x4){0.f, 0.f, 0.f, 0.f};

      const _Float16* hbp = &S.hbuf[tt & 1][0];
#pragma unroll
      for (int cc = 0; cc < 8; cc++) {
        f16x8 bfr = *(const f16x8*)(hbp + chain * 272 + cc * 32 + kg * 8);
        if (cc < 6) {
#pragma unroll
          for (int ti = 0; ti < 8; ti++)
            cacc[ti] = MFMA16(wA[cc][ti], bfr, cacc[ti]);
        } else {
#pragma unroll
          for (int ti = 0; ti < 8; ti++) {
            f16x8 av = *(const f16x8*)&S.ldsA[wv * 8192 + (ti * 2 + (cc - 6)) * 512 + l * 8];
            cacc[ti] = MFMA16(av, bfr, cacc[ti]);
          }
        }
      }
    }

    // Head (layer1, waves 0-1): one-step-delayed a -> y[tt-1].
    if (LAYER == 1 && wv < 2 && tt >= 1) {
      f32x4 hcc = (f32x4){hb0, hb1, hb2, hb3};
      const _Float16* abp = &S.abuf[(tt + 1) & 1][0];
#pragma unroll
      for (int cc = 0; cc < 8; cc++) {
        f16x8 bfr = *(const f16x8*)(abp + chain * 272 + cc * 32 + kg * 8);
        f16x8 av = *(const f16x8*)&S.headA[(wv * 8 + cc) * 512 + l * 8];
        hcc = MFMA16(av, bfr, hcc);
      }
      if (((l >> 2) & 3) == 0) {
        int o0 = wv * 16 + rg4x4;
        size_t ybase = ((size_t)bglob * OC) * T_SEQ + (size_t)chunk * Tc + tt - 1;
#pragma unroll
        for (int r = 0; r < 4; r++)
          if (o0 + r < OC) P.y[ybase + (size_t)(o0 + r) * T_SEQ] = hcc[r];
      }
    }

    if (tt < Tc) {
      // Literal-index gate extraction (no dynamic register indexing!).
      float gI0, gI1, gF0, gF1, gG0, gG1, gO0, gO1;
#define EXTRACT(HH, RL)                                             \
  { gI0 = cacc[0 + HH][RL]; gI1 = cacc[0 + HH][RL + 1];             \
    gF0 = cacc[2 + HH][RL]; gF1 = cacc[2 + HH][RL + 1];             \
    gG0 = cacc[4 + HH][RL]; gG1 = cacc[4 + HH][RL + 1];             \
    gO0 = cacc[6 + HH][RL]; gO1 = cacc[6 + HH][RL + 1]; }
      if (hh == 0) { if (rlo == 0) EXTRACT(0, 0) else EXTRACT(0, 2) }
      else         { if (rlo == 0) EXTRACT(1, 0) else EXTRACT(1, 2) }
#undef EXTRACT
      f16x2 xI = __builtin_bit_cast(f16x2, xwg[0]);
      f16x2 xF = __builtin_bit_cast(f16x2, xwg[1]);
      f16x2 xG = __builtin_bit_cast(f16x2, xwg[2]);
      f16x2 xO = __builtin_bit_cast(f16x2, xwg[3]);
      gI0 += (float)xI[0]; gI1 += (float)xI[1];
      gF0 += (float)xF[0]; gF1 += (float)xF[1];
      gG0 += (float)xG[0]; gG1 += (float)xG[1];
      gO0 += (float)xO[0]; gO1 += (float)xO[1];

      float iv0 = sigf(gI0), iv1 = sigf(gI1);
      float fv0 = sigf(gF0), fv1 = sigf(gF1);
      float gv0 = tanhnf(gG0), gv1 = tanhnf(gG1);
      float ov0 = sigf(gO0), ov1 = sigf(gO1);
      c0 = fv0 * c0 + iv0 * gv0;
      c1 = fv1 * c1 + iv1 * gv1;
      h0v = ov0 * tanhnf(c0);
      h1v = ov1 * tanhnf(c1);
      f16x2 hp = (f16x2){(_Float16)h0v, (_Float16)h1v};
      *(f16x2*)&S.hbuf[(tt + 1) & 1][chain * 272 + ch0] = hp;
      if (LAYER == 0) {
        *(f16x2*)(P.h1w + ((size_t)tt * NB + bglob) * HID + ch0) = hp;
      } else {
        float a0 = h0v > 0.f ? h0v : 0.01f * h0v;
        float a1 = h1v > 0.f ? h1v : 0.01f * h1v;
        *(f16x2*)&S.abuf[tt & 1][chain * 272 + ch0] = (f16x2){(_Float16)a0, (_Float16)a1};
      }
    }
    __syncthreads();
  }
  cs[bglob * HID + ch0] = c0;  cs[bglob * HID + ch0 + 1] = c1;
  hs[bglob * HID + ch0] = h0v; hs[bglob * HID + ch0 + 1] = h1v;
}

// ---------------------------------------------------------------------------
// GEMM0: xw0[t][chain][row] = Wih0p(1024x32) . x_t(32 x 64chains) + bs0.
// One block per t (local). 8 waves x 8 Mtiles x 4 Ntiles x K=32.
// ---------------------------------------------------------------------------
__device__ void role_g0(_Float16* xs, const Params& P, int tl) {
  int chunk = P.L + 1;
  if (chunk < 0 || chunk >= P.nch) return;
  int tglob = chunk * P.Tc + tl;
  int tid = threadIdx.x, wv = tid >> 6, l = tid & 63, lcol = l & 15, kg = l >> 4;

  for (int i = tid; i < 1024; i += 512) {
    int b = i >> 4, cin = i & 15;
    xs[b * 40 + cin] = (_Float16)P.x[((size_t)b * INCH + cin) * T_SEQ + tglob];
    xs[b * 40 + 16 + cin] = (_Float16)0.f;
  }
  __syncthreads();

  f32x4 cc4[8][4];
#pragma unroll
  for (int mt = 0; mt < 8; mt++) {
    int rowb = wv * 128 + mt * 16;
    f32x4 bv = *(const f32x4*)(P.bs0 + rowb + kg * 4);
#pragma unroll
    for (int nt = 0; nt < 4; nt++) cc4[mt][nt] = bv;
  }
  f16x8 bfr[4];
#pragma unroll
  for (int nt = 0; nt < 4; nt++)
    bfr[nt] = *(const f16x8*)(xs + (nt * 16 + lcol) * 40 + kg * 8);
#pragma unroll
  for (int mt = 0; mt < 8; mt++) {
    int rowb = wv * 128 + mt * 16;
    f16x8 av = *(const f16x8*)(P.wi0p + (rowb + lcol) * 32 + kg * 8);
#pragma unroll
    for (int nt = 0; nt < 4; nt++) cc4[mt][nt] = MFMA16(av, bfr[nt], cc4[mt][nt]);
  }
#pragma unroll
  for (int mt = 0; mt < 8; mt++) {
    int rowb = wv * 128 + mt * 16 + kg * 4;
#pragma unroll
    for (int nt = 0; nt < 4; nt++) {
      int chainN = nt * 16 + lcol;
      f16x4 pk = {(_Float16)cc4[mt][nt][0], (_Float16)cc4[mt][nt][1],
                  (_Float16)cc4[mt][nt][2], (_Float16)cc4[mt][nt][3]};
      *(f16x4*)(P.xw0w + ((size_t)tl * NB + chainN) * G4 + rowb) = pk;
    }
  }
}

// ---------------------------------------------------------------------------
// GEMM1: xw1[t][chain][row] = Wih1(1024x256) . h1_t(256 x 64chains) + bs1.
// Block = (t, 256-row slab): idx = t*4 + slab. 8 waves x 2 Mtiles x 4 Nt x K8.
// ---------------------------------------------------------------------------
__device__ void role_g1(const Params& P, int idx) {
  int chunk = P.L - 1;
  if (chunk < 0 || chunk >= P.nch) return;
  int t = idx >> 2, slab = idx & 3;
  int tid = threadIdx.x, wv = tid >> 6, l = tid & 63, lcol = l & 15, kg = l >> 4;

  f32x4 cc4[2][4];
#pragma unroll
  for (int mi = 0; mi < 2; mi++) {
    int rowb = slab * 256 + (wv * 2 + mi) * 16;
    f32x4 bv = *(const f32x4*)(P.bs1 + rowb + kg * 4);
#pragma unroll
    for (int nt = 0; nt < 4; nt++) cc4[mi][nt] = bv;
  }
  for (int cc = 0; cc < 8; cc++) {
    f16x8 bfr[4];
#pragma unroll
    for (int nt = 0; nt < 4; nt++)
      bfr[nt] = *(const f16x8*)(P.h1r + ((size_t)t * NB + nt * 16 + lcol) * HID + cc * 32 + kg * 8);
#pragma unroll
    for (int mi = 0; mi < 2; mi++) {
      int rowb = slab * 256 + (wv * 2 + mi) * 16;
      f16x8 av = *(const f16x8*)(P.wi1 + (rowb + lcol) * HID + cc * 32 + kg * 8);
#pragma unroll
      for (int nt = 0; nt < 4; nt++) cc4[mi][nt] = MFMA16(av, bfr[nt], cc4[mi][nt]);
    }
  }
#pragma unroll
  for (int mi = 0; mi < 2; mi++) {
    int rowb = slab * 256 + (wv * 2 + mi) * 16 + kg * 4;
#pragma unroll
    for (int nt = 0; nt < 4; nt++) {
      int chainN = nt * 16 + lcol;
      f16x4 pk = {(_Float16)cc4[mi][nt][0], (_Float16)cc4[mi][nt][1],
                  (_Float16)cc4[mi][nt][2], (_Float16)cc4[mi][nt][3]};
      *(f16x4*)(P.xw1w + ((size_t)t * NB + chainN) * G4 + rowb) = pk;
    }
  }
}

__global__ __launch_bounds__(512, 2) void fused_kernel(Params P) {
  __shared__ Smem S;
  int bid = blockIdx.x;
  if (bid < 16)             role_rec<0>(S.r, P.L, P, bid);
  else if (bid < 32)        role_rec<1>(S.r, P.L - 2, P, bid - 16);
  else if (bid < 32 + P.Tc) role_g0(S.g0.xs, P, bid - 32);
  else                      role_g1(P, bid - 32 - P.Tc);
}

// ---------------------------------------------------------------------------
__global__ void prep_kernel(const float* Wih0, const float* Whh0,
                            const float* bih0, const float* bhh0,
                            const float* Wih1, const float* Whh1,
                            const float* bih1, const float* bhh1,
                            const float* Whead,
                            _Float16* wh0, _Float16* wh1, _Float16* wi0p,
                            _Float16* wi1, _Float16* whd,
                            float* bs0, float* bs1) {
  int i = blockIdx.x * blockDim.x + threadIdx.x;
  if (i < G4 * HID) {
    wh0[i] = (_Float16)Whh0[i];
    wh1[i] = (_Float16)Whh1[i];
    wi1[i] = (_Float16)Wih1[i];
  }
  if (i < G4 * 32) {
    int r = i >> 5, k = i & 31;
    wi0p[i] = (k < INCH) ? (_Float16)Wih0[r * INCH + k] : (_Float16)0.f;
  }
  if (i < OC * HID) whd[i] = (_Float16)Whead[i];
  if (i < G4) { bs0[i] = bih0[i] + bhh0[i]; bs1[i] = bih1[i] + bhh1[i]; }
}

// ---------------------------------------------------------------------------
extern "C" void kernel_launch(void* const* d_in, const int* in_sizes, int n_in,
                              void* d_out, int out_size, void* d_ws, size_t ws_size,
                              hipStream_t stream) {
  const float* x     = (const float*)d_in[0];
  const float* Wih0  = (const float*)d_in[1];
  const float* Whh0  = (const float*)d_in[2];
  const float* bih0  = (const float*)d_in[3];
  const float* bhh0  = (const float*)d_in[4];
  const float* Wih1  = (const float*)d_in[5];
  const float* Whh1  = (const float*)d_in[6];
  const float* bih1  = (const float*)d_in[7];
  const float* bhh1  = (const float*)d_in[8];
  const float* Whead = (const float*)d_in[9];
  const float* bhead = (const float*)d_in[10];
  float* y = (float*)d_out;

  char* ws = (char*)d_ws;
  size_t cur = 0;
  auto alloc = [&](size_t sz) -> char* {
    char* p = ws + cur;
    cur = (cur + sz + 255) & ~(size_t)255;
    return p;
  };
  _Float16* wh0  = (_Float16*)alloc(G4 * HID * 2);
  _Float16* wh1  = (_Float16*)alloc(G4 * HID * 2);
  _Float16* wi0p = (_Float16*)alloc(G4 * 32 * 2);
  _Float16* wi1  = (_Float16*)alloc(G4 * HID * 2);
  _Float16* whd  = (_Float16*)alloc(OC * HID * 2);
  float* bs0 = (float*)alloc(G4 * 4);
  float* bs1 = (float*)alloc(G4 * 4);
  float* h0s = (float*)alloc(NB * HID * 4);
  float* c0s = (float*)alloc(NB * HID * 4);
  float* h1s = (float*)alloc(NB * HID * 4);
  float* c1s = (float*)alloc(NB * HID * 4);
  size_t fixed = cur;

  int Tc = 256;
  while (Tc > 32) {
    size_t need = fixed + 2 * ((size_t)Tc * NB * HID * 2 + 512) +
                  4 * ((size_t)Tc * NB * G4 * 2 + 512);
    if (need <= ws_size) break;
    Tc >>= 1;
  }
  _Float16* h1b[2];
  _Float16* xw0b[2];
  _Float16* xw1b[2];
  h1b[0]  = (_Float16*)alloc((size_t)Tc * NB * HID * 2);
  h1b[1]  = (_Float16*)alloc((size_t)Tc * NB * HID * 2);
  xw0b[0] = (_Float16*)alloc((size_t)Tc * NB * G4 * 2);
  xw0b[1] = (_Float16*)alloc((size_t)Tc * NB * G4 * 2);
  xw1b[0] = (_Float16*)alloc((size_t)Tc * NB * G4 * 2);
  xw1b[1] = (_Float16*)alloc((size_t)Tc * NB * G4 * 2);

  const int nch = T_SEQ / Tc;

  prep_kernel<<<(G4 * HID + 255) / 256, 256, 0, stream>>>(
      Wih0, Whh0, bih0, bhh0, Wih1, Whh1, bih1, bhh1, Whead,
      wh0, wh1, wi0p, wi1, whd, bs0, bs1);

  const int grid = 32 + 5 * Tc;
  for (int L = -1; L <= nch + 1; ++L) {
    Params P;
    P.x = x;
    P.wh0 = wh0; P.wh1 = wh1; P.wi0p = wi0p; P.wi1 = wi1; P.whd = whd;
    P.bs0 = bs0; P.bs1 = bs1; P.bhd = bhead;
    P.h0s = h0s; P.c0s = c0s; P.h1s = h1s; P.c1s = c1s;
    P.h1w  = h1b[(L & 1 + 2) & 1];          // chunk L
    P.h1w  = h1b[((L % 2) + 2) % 2];
    P.h1r  = h1b[(((L - 1) % 2) + 2) % 2];  // chunk L-1 (GEMM1 read)
    P.xw0w = xw0b[(((L + 1) % 2) + 2) % 2]; // chunk L+1
    P.xw0r = xw0b[((L % 2) + 2) % 2];       // chunk L
    P.xw1w = xw1b[(((L - 1) % 2) + 2) % 2]; // chunk L-1
    P.xw1r = xw1b[((L % 2) + 2) % 2];       // chunk L-2 ((L-2)%2 == L%2)
    P.y = y;
    P.L = L; P.Tc = Tc; P.nch = nch;
    fused_kernel<<<grid, 512, 0, stream>>>(P);
  }
}